// Round 1
// baseline (1149.569 us; speedup 1.0000x reference)
//
#include <hip/hip_runtime.h>
#include <cstdint>
#include <cstddef>

// MultiHeadAttention fused block — round 1: correct fp32 baseline.
// Assumptions under test:
//   * att_mask (input 3) is raw bool bytes -> const uint8_t*, nonzero = masked
//   * d_out = [out (4*2048*512 f32)] ++ [attn (4*8*2048*2048 f32)]
//   * ws_size >= 64 MiB (q,k,v,ctx scratch; pre-LN reuses q buffer)

constexpr int D_MODEL_C = 512;
constexpr int S_LEN     = 2048;
constexpr int BATCH     = 4;
constexpr int NHEAD     = 8;
constexpr int DK        = 64;
constexpr int ROWS      = BATCH * S_LEN;          // 8192
constexpr int BHC       = BATCH * NHEAD;          // 32
constexpr size_t OUT_ELEMS  = (size_t)ROWS * D_MODEL_C;          // 4,194,304
constexpr size_t HEAD_ELEMS = (size_t)BHC * S_LEN * DK;          // 4,194,304

// ---------------------------------------------------------------------------
// Projection GEMM: Y[bh][s][dk] = X @ W + b
// X: [8192][512] row-major, W: [512][512] ([in][out]), Y: head-split layout.
__global__ __launch_bounds__(256)
void proj_gemm(const float* __restrict__ X, const float* __restrict__ W,
               const float* __restrict__ bias, float* __restrict__ Y)
{
    __shared__ float As[16][65];   // [k][m], padded
    __shared__ float Bs[16][64];   // [k][n]
    const int tid = threadIdx.x;
    const int m0 = blockIdx.y * 64;
    const int n0 = blockIdx.x * 64;
    const int tx = tid & 15, ty = tid >> 4;
    float acc[4][4] = {};

    for (int k0 = 0; k0 < D_MODEL_C; k0 += 16) {
#pragma unroll
        for (int i = 0; i < 4; ++i) {
            int idx = tid + i * 256;
            int k = idx & 15, m = idx >> 4;
            As[k][m] = X[(size_t)(m0 + m) * D_MODEL_C + k0 + k];
        }
#pragma unroll
        for (int i = 0; i < 4; ++i) {
            int idx = tid + i * 256;
            int n = idx & 63, k = idx >> 6;
            Bs[k][n] = W[(size_t)(k0 + k) * D_MODEL_C + n0 + n];
        }
        __syncthreads();
#pragma unroll
        for (int k = 0; k < 16; ++k) {
            float a[4], b[4];
#pragma unroll
            for (int i = 0; i < 4; ++i) a[i] = As[k][ty * 4 + i];
#pragma unroll
            for (int j = 0; j < 4; ++j) b[j] = Bs[k][tx * 4 + j];
#pragma unroll
            for (int i = 0; i < 4; ++i)
#pragma unroll
                for (int j = 0; j < 4; ++j)
                    acc[i][j] = fmaf(a[i], b[j], acc[i][j]);
        }
        __syncthreads();
    }

    const int b = m0 >> 11;          // tile never crosses batch (2048 % 64 == 0)
    const int h = n0 >> 6;           // tile never crosses head  (64-col tiles)
#pragma unroll
    for (int i = 0; i < 4; ++i) {
        int mm = m0 + ty * 4 + i;
        int s = mm & (S_LEN - 1);
#pragma unroll
        for (int j = 0; j < 4; ++j) {
            int n = n0 + tx * 4 + j;
            int d = n & 63;
            Y[(((size_t)b * NHEAD + h) * S_LEN + s) * DK + d] = acc[i][j] + bias[n];
        }
    }
}

// ---------------------------------------------------------------------------
// Scores: attn_raw[bh][q][kk] = (q . k) / 8, masked -> -1e9
__global__ __launch_bounds__(256)
void score_kernel(const float* __restrict__ q, const float* __restrict__ k,
                  const uint8_t* __restrict__ mask, float* __restrict__ attn)
{
    __shared__ float Qs[64][65];  // [d][m]
    __shared__ float Ks[64][65];  // [d][n]
    const int tid = threadIdx.x;
    const int bh = blockIdx.z;
    const int q0 = blockIdx.y * 64;
    const int n0 = blockIdx.x * 64;
    const int b  = bh >> 3;

    const size_t qbase = ((size_t)bh * S_LEN + q0) * DK;
    const size_t kbase = ((size_t)bh * S_LEN + n0) * DK;
#pragma unroll
    for (int i = 0; i < 16; ++i) {
        int idx = tid + i * 256;
        int d = idx & 63, m = idx >> 6;
        Qs[d][m] = q[qbase + (size_t)m * DK + d];
        Ks[d][m] = k[kbase + (size_t)m * DK + d];
    }
    __syncthreads();

    const int tx = tid & 15, ty = tid >> 4;
    float acc[4][4] = {};
#pragma unroll 16
    for (int d = 0; d < 64; ++d) {
        float a[4], bb[4];
#pragma unroll
        for (int i = 0; i < 4; ++i) a[i] = Qs[d][ty * 4 + i];
#pragma unroll
        for (int j = 0; j < 4; ++j) bb[j] = Ks[d][tx * 4 + j];
#pragma unroll
        for (int i = 0; i < 4; ++i)
#pragma unroll
            for (int j = 0; j < 4; ++j)
                acc[i][j] = fmaf(a[i], bb[j], acc[i][j]);
    }

#pragma unroll
    for (int i = 0; i < 4; ++i) {
        const int row = q0 + ty * 4 + i;
        const uchar4 mk = *reinterpret_cast<const uchar4*>(
            &mask[((size_t)b * S_LEN + row) * S_LEN + n0 + tx * 4]);
        float4 o;
        o.x = mk.x ? -1e9f : acc[i][0] * 0.125f;
        o.y = mk.y ? -1e9f : acc[i][1] * 0.125f;
        o.z = mk.z ? -1e9f : acc[i][2] * 0.125f;
        o.w = mk.w ? -1e9f : acc[i][3] * 0.125f;
        *reinterpret_cast<float4*>(
            &attn[((size_t)bh * S_LEN + row) * S_LEN + n0 + tx * 4]) = o;
    }
}

// ---------------------------------------------------------------------------
// Row softmax in place over attn rows of length 2048.
__global__ __launch_bounds__(256)
void softmax_kernel(float* __restrict__ attn)
{
    const size_t row = blockIdx.x;
    float* p = attn + row * S_LEN;
    const int tid = threadIdx.x;
    const int wave = tid >> 6;

    float4 a = reinterpret_cast<float4*>(p)[tid];
    float4 b = reinterpret_cast<float4*>(p)[tid + 256];

    float m = fmaxf(fmaxf(fmaxf(a.x, a.y), fmaxf(a.z, a.w)),
                    fmaxf(fmaxf(b.x, b.y), fmaxf(b.z, b.w)));
#pragma unroll
    for (int off = 32; off; off >>= 1) m = fmaxf(m, __shfl_xor(m, off));
    __shared__ float redm[4];
    if ((tid & 63) == 0) redm[wave] = m;
    __syncthreads();
    m = fmaxf(fmaxf(redm[0], redm[1]), fmaxf(redm[2], redm[3]));

    a.x = __expf(a.x - m); a.y = __expf(a.y - m);
    a.z = __expf(a.z - m); a.w = __expf(a.w - m);
    b.x = __expf(b.x - m); b.y = __expf(b.y - m);
    b.z = __expf(b.z - m); b.w = __expf(b.w - m);

    float s = a.x + a.y + a.z + a.w + b.x + b.y + b.z + b.w;
#pragma unroll
    for (int off = 32; off; off >>= 1) s += __shfl_xor(s, off);
    __shared__ float reds[4];
    if ((tid & 63) == 0) reds[wave] = s;
    __syncthreads();
    s = reds[0] + reds[1] + reds[2] + reds[3];

    const float inv = 1.0f / s;
    a.x *= inv; a.y *= inv; a.z *= inv; a.w *= inv;
    b.x *= inv; b.y *= inv; b.z *= inv; b.w *= inv;
    reinterpret_cast<float4*>(p)[tid]       = a;
    reinterpret_cast<float4*>(p)[tid + 256] = b;
}

// ---------------------------------------------------------------------------
// PV: ctx[b][s][h*64+d] = attn[bh][s][:] @ v[bh][:][d]
__global__ __launch_bounds__(256)
void pv_kernel(const float* __restrict__ attn, const float* __restrict__ v,
               float* __restrict__ ctx)
{
    __shared__ float As[16][65];   // [kk][m]
    __shared__ float Bs[16][64];   // [kk][d]
    const int tid = threadIdx.x;
    const int bh = blockIdx.y;
    const int q0 = blockIdx.x * 64;
    const int tx = tid & 15, ty = tid >> 4;
    float acc[4][4] = {};

    for (int k0 = 0; k0 < S_LEN; k0 += 16) {
#pragma unroll
        for (int i = 0; i < 4; ++i) {
            int idx = tid + i * 256;
            int kk = idx & 15, m = idx >> 4;
            As[kk][m] = attn[((size_t)bh * S_LEN + q0 + m) * S_LEN + k0 + kk];
        }
#pragma unroll
        for (int i = 0; i < 4; ++i) {
            int idx = tid + i * 256;
            int d = idx & 63, kk = idx >> 6;
            Bs[kk][d] = v[((size_t)bh * S_LEN + k0 + kk) * DK + d];
        }
        __syncthreads();
#pragma unroll
        for (int kk = 0; kk < 16; ++kk) {
            float a[4], bb[4];
#pragma unroll
            for (int i = 0; i < 4; ++i) a[i] = As[kk][ty * 4 + i];
#pragma unroll
            for (int j = 0; j < 4; ++j) bb[j] = Bs[kk][tx * 4 + j];
#pragma unroll
            for (int i = 0; i < 4; ++i)
#pragma unroll
                for (int j = 0; j < 4; ++j)
                    acc[i][j] = fmaf(a[i], bb[j], acc[i][j]);
        }
        __syncthreads();
    }

    const int b = bh >> 3, h = bh & 7;
#pragma unroll
    for (int i = 0; i < 4; ++i) {
        int s = q0 + ty * 4 + i;
#pragma unroll
        for (int j = 0; j < 4; ++j)
            ctx[((size_t)b * S_LEN + s) * D_MODEL_C + h * DK + tx * 4 + j] = acc[i][j];
    }
}

// ---------------------------------------------------------------------------
// Output projection + bias + residual: pre = ctx @ Wo + bo + resid
__global__ __launch_bounds__(256)
void out_gemm(const float* __restrict__ X, const float* __restrict__ W,
              const float* __restrict__ bias, const float* __restrict__ resid,
              float* __restrict__ Y)
{
    __shared__ float As[16][65];
    __shared__ float Bs[16][64];
    const int tid = threadIdx.x;
    const int m0 = blockIdx.y * 64;
    const int n0 = blockIdx.x * 64;
    const int tx = tid & 15, ty = tid >> 4;
    float acc[4][4] = {};

    for (int k0 = 0; k0 < D_MODEL_C; k0 += 16) {
#pragma unroll
        for (int i = 0; i < 4; ++i) {
            int idx = tid + i * 256;
            int k = idx & 15, m = idx >> 4;
            As[k][m] = X[(size_t)(m0 + m) * D_MODEL_C + k0 + k];
        }
#pragma unroll
        for (int i = 0; i < 4; ++i) {
            int idx = tid + i * 256;
            int n = idx & 63, k = idx >> 6;
            Bs[k][n] = W[(size_t)(k0 + k) * D_MODEL_C + n0 + n];
        }
        __syncthreads();
#pragma unroll
        for (int k = 0; k < 16; ++k) {
            float a[4], b[4];
#pragma unroll
            for (int i = 0; i < 4; ++i) a[i] = As[k][ty * 4 + i];
#pragma unroll
            for (int j = 0; j < 4; ++j) b[j] = Bs[k][tx * 4 + j];
#pragma unroll
            for (int i = 0; i < 4; ++i)
#pragma unroll
                for (int j = 0; j < 4; ++j)
                    acc[i][j] = fmaf(a[i], b[j], acc[i][j]);
        }
        __syncthreads();
    }

#pragma unroll
    for (int i = 0; i < 4; ++i) {
        int mm = m0 + ty * 4 + i;
#pragma unroll
        for (int j = 0; j < 4; ++j) {
            int n = n0 + tx * 4 + j;
            Y[(size_t)mm * D_MODEL_C + n] =
                acc[i][j] + bias[n] + resid[(size_t)mm * D_MODEL_C + n];
        }
    }
}

// ---------------------------------------------------------------------------
// LayerNorm over rows of 512 (weight=1, bias=0, eps=1e-5, biased variance).
__global__ __launch_bounds__(128)
void ln_kernel(const float* __restrict__ pre, float* __restrict__ out)
{
    const size_t row = blockIdx.x;
    const int tid = threadIdx.x;
    const int wave = tid >> 6;
    float4 x = reinterpret_cast<const float4*>(pre + row * D_MODEL_C)[tid];

    float s = x.x + x.y + x.z + x.w;
#pragma unroll
    for (int off = 32; off; off >>= 1) s += __shfl_xor(s, off);
    __shared__ float r1[2];
    if ((tid & 63) == 0) r1[wave] = s;
    __syncthreads();
    const float mean = (r1[0] + r1[1]) * (1.0f / 512.0f);

    float dx = x.x - mean, dy = x.y - mean, dz = x.z - mean, dw = x.w - mean;
    float sq = dx * dx + dy * dy + dz * dz + dw * dw;
#pragma unroll
    for (int off = 32; off; off >>= 1) sq += __shfl_xor(sq, off);
    __shared__ float r2[2];
    if ((tid & 63) == 0) r2[wave] = sq;
    __syncthreads();
    const float var = (r2[0] + r2[1]) * (1.0f / 512.0f);
    const float inv = rsqrtf(var + 1e-5f);

    float4 y;
    y.x = dx * inv; y.y = dy * inv; y.z = dz * inv; y.w = dw * inv;
    reinterpret_cast<float4*>(out + row * D_MODEL_C)[tid] = y;
}

// ---------------------------------------------------------------------------
extern "C" void kernel_launch(void* const* d_in, const int* in_sizes, int n_in,
                              void* d_out, int out_size, void* d_ws, size_t ws_size,
                              hipStream_t stream)
{
    (void)in_sizes; (void)n_in; (void)out_size; (void)ws_size;

    const float*   Qin  = (const float*)d_in[0];
    const float*   Kin  = (const float*)d_in[1];
    const float*   Vin  = (const float*)d_in[2];
    const uint8_t* mask = (const uint8_t*)d_in[3];
    const float*   Wq   = (const float*)d_in[4];
    const float*   bq   = (const float*)d_in[5];
    const float*   Wk   = (const float*)d_in[6];
    const float*   bk   = (const float*)d_in[7];
    const float*   Wv   = (const float*)d_in[8];
    const float*   bv   = (const float*)d_in[9];
    const float*   Wo   = (const float*)d_in[10];
    const float*   bo   = (const float*)d_in[11];

    float* out  = (float*)d_out;
    float* attn = out + OUT_ELEMS;

    float* ws  = (float*)d_ws;
    float* q   = ws;                    // HEAD_ELEMS
    float* k   = ws + HEAD_ELEMS;       // HEAD_ELEMS
    float* v   = ws + 2 * HEAD_ELEMS;   // HEAD_ELEMS
    float* ctx = ws + 3 * HEAD_ELEMS;   // OUT_ELEMS
    float* pre = q;                     // reuse q buffer after scores are done

    dim3 gProj(D_MODEL_C / 64, ROWS / 64);          // (8, 128)
    proj_gemm<<<gProj, 256, 0, stream>>>(Qin, Wq, bq, q);
    proj_gemm<<<gProj, 256, 0, stream>>>(Kin, Wk, bk, k);
    proj_gemm<<<gProj, 256, 0, stream>>>(Vin, Wv, bv, v);

    dim3 gScore(S_LEN / 64, S_LEN / 64, BHC);       // (32, 32, 32)
    score_kernel<<<gScore, 256, 0, stream>>>(q, k, mask, attn);

    softmax_kernel<<<BHC * S_LEN, 256, 0, stream>>>(attn);

    dim3 gPV(S_LEN / 64, BHC);                      // (32, 32)
    pv_kernel<<<gPV, 256, 0, stream>>>(attn, v, ctx);

    out_gemm<<<gProj, 256, 0, stream>>>(ctx, Wo, bo, Qin, pre);

    ln_kernel<<<ROWS, 128, 0, stream>>>(pre, out);
}

// Round 2
// 639.591 us; speedup vs baseline: 1.7974x; 1.7974x over previous
//
#include <hip/hip_runtime.h>
#include <hip/hip_bf16.h>
#include <cstdint>
#include <cstddef>

// Round 2: full bf16-MFMA pipeline.
//  wconv:      W[k][n] f32 -> Wt[n][k] bf16 (x4 matrices)         (ws)
//  proj_mfma:  q/k/v bf16 [bh][s][64] (q pre-scaled by 0.125)     (ws)
//  vtrans:     v -> vt [bh][64][s] bf16                           (ws)
//  score_mfma: raw masked scores f32 -> attn region of d_out
//  smpv_fused: in-place softmax on attn + PV MFMA -> ctx bf16     (ws)
//  out_mfma:   ctx @ Wo + bo + resid -> pre f32                   (ws)
//  ln_kernel:  LayerNorm -> out
// ws usage: 2+8+8+8+8+8+16 = 58 MB (proven >= 64 MB available).

typedef __attribute__((ext_vector_type(8)))  short short8v;
typedef __attribute__((ext_vector_type(4)))  float f32x4;
typedef __attribute__((ext_vector_type(16))) float f32x16;

constexpr int DM = 512, S = 2048, BATCH = 4, NHEAD = 8, DK = 64;
constexpr int ROWS = BATCH * S;                 // 8192
constexpr int BH   = BATCH * NHEAD;             // 32
constexpr size_t OUT_ELEMS = (size_t)ROWS * DM; // 4,194,304

#define ZERO16 {0.f,0.f,0.f,0.f,0.f,0.f,0.f,0.f,0.f,0.f,0.f,0.f,0.f,0.f,0.f,0.f}

__device__ __forceinline__ unsigned short f2bf(float f) {
    union { __hip_bfloat16 b; unsigned short u; } c;
    c.b = __float2bfloat16(f);   // RNE
    return c.u;
}

// ---------------------------------------------------------------------------
// Transpose-convert the 4 weight matrices: W[512][512] f32 -> Wt[n][k] bf16.
__global__ __launch_bounds__(256)
void wconv(const float* __restrict__ Wq, const float* __restrict__ Wk,
           const float* __restrict__ Wv, const float* __restrict__ Wo,
           unsigned short* __restrict__ wt)
{
    __shared__ float T[32][33];
    const float* srcs[4] = {Wq, Wk, Wv, Wo};
    const float* W = srcs[blockIdx.z];
    unsigned short* out = wt + (size_t)blockIdx.z * DM * DM;
    const int r0 = blockIdx.y * 32, c0 = blockIdx.x * 32;
    const int tid = threadIdx.x;
#pragma unroll
    for (int i = 0; i < 4; ++i) {
        int lin = tid + i * 256; int r = lin >> 5, c = lin & 31;
        T[r][c] = W[(size_t)(r0 + r) * DM + c0 + c];
    }
    __syncthreads();
#pragma unroll
    for (int i = 0; i < 4; ++i) {
        int lin = tid + i * 256; int rn = lin >> 5, ck = lin & 31;
        out[(size_t)(c0 + rn) * DM + r0 + ck] = f2bf(T[ck][rn]);
    }
}

// ---------------------------------------------------------------------------
// Projection: Y_bf16[bh][s][64] = (X f32 * scale) @ W + bias*scale
// A-frag (32x32x16): lane l holds X[m0+(l&31)][k0 + 8*(l>>5) + j], j=0..7.
// B-frag: lane l holds Wt[n0+(l&31)][k0 + 8*(l>>5) + j] (contiguous 16B).
__global__ __launch_bounds__(256)
void proj_mfma(const float* __restrict__ X, const unsigned short* __restrict__ Wt,
               const float* __restrict__ bias, unsigned short* __restrict__ Y,
               float scale)
{
    const int tid = threadIdx.x, wv = tid >> 6, l = tid & 63, lr = l & 31, lh = l >> 5;
    const int m0 = blockIdx.y * 128 + wv * 32;
    const int n0 = blockIdx.x * 64;
    const float* xp = X + (size_t)(m0 + lr) * DM + 8 * lh;
    const unsigned short* w0 = Wt + (size_t)(n0 + lr) * DM + 8 * lh;
    const unsigned short* w1 = w0 + (size_t)32 * DM;
    f32x16 acc0 = ZERO16, acc1 = ZERO16;
#pragma unroll 8
    for (int t = 0; t < 32; ++t) {
        float4 xa = *reinterpret_cast<const float4*>(xp + 16 * t);
        float4 xb = *reinterpret_cast<const float4*>(xp + 16 * t + 4);
        short8v a;
        a[0] = (short)f2bf(xa.x * scale); a[1] = (short)f2bf(xa.y * scale);
        a[2] = (short)f2bf(xa.z * scale); a[3] = (short)f2bf(xa.w * scale);
        a[4] = (short)f2bf(xb.x * scale); a[5] = (short)f2bf(xb.y * scale);
        a[6] = (short)f2bf(xb.z * scale); a[7] = (short)f2bf(xb.w * scale);
        short8v b0 = *reinterpret_cast<const short8v*>(w0 + 16 * t);
        short8v b1 = *reinterpret_cast<const short8v*>(w1 + 16 * t);
        acc0 = __builtin_amdgcn_mfma_f32_32x32x16_bf16(a, b0, acc0, 0, 0, 0);
        acc1 = __builtin_amdgcn_mfma_f32_32x32x16_bf16(a, b1, acc1, 0, 0, 0);
    }
#pragma unroll
    for (int j = 0; j < 2; ++j) {
        const f32x16 acc = j ? acc1 : acc0;
        const int n = n0 + 32 * j + lr;
        const float bv = bias[n] * scale;
        const int h = n >> 6, d = n & 63;
#pragma unroll
        for (int r = 0; r < 16; ++r) {
            const int m = m0 + (r & 3) + 8 * (r >> 2) + 4 * lh;
            const int b = m >> 11, s = m & (S - 1);
            Y[(((size_t)b * NHEAD + h) * S + s) * DK + d] = f2bf(acc[r] + bv);
        }
    }
}

// ---------------------------------------------------------------------------
// v[bh][s][64] -> vt[bh][64][s] (bf16 transpose)
__global__ __launch_bounds__(256)
void vtrans(const unsigned short* __restrict__ v, unsigned short* __restrict__ vt)
{
    __shared__ unsigned short T[64][65];
    const int bh = blockIdx.y, s0 = blockIdx.x * 64, tid = threadIdx.x;
#pragma unroll
    for (int i = 0; i < 4; ++i) {
        int lin = tid + i * 256; int sr = lin >> 4, c4 = (lin & 15) * 4;
        ushort4 u = *reinterpret_cast<const ushort4*>(
            v + ((size_t)bh * S + s0 + sr) * DK + c4);
        T[sr][c4] = u.x; T[sr][c4 + 1] = u.y; T[sr][c4 + 2] = u.z; T[sr][c4 + 3] = u.w;
    }
    __syncthreads();
#pragma unroll
    for (int i = 0; i < 4; ++i) {
        int lin = tid + i * 256; int d = lin >> 4, c4 = (lin & 15) * 4;
        ushort4 w;
        w.x = T[c4][d]; w.y = T[c4 + 1][d]; w.z = T[c4 + 2][d]; w.w = T[c4 + 3][d];
        *reinterpret_cast<ushort4*>(vt + ((size_t)bh * DK + d) * S + s0 + c4) = w;
    }
}

// ---------------------------------------------------------------------------
// Scores (q pre-scaled): attn[bh][m][n] = q[m].k[n], masked -> -1e9. Raw f32.
__global__ __launch_bounds__(256)
void score_mfma(const unsigned short* __restrict__ q, const unsigned short* __restrict__ k,
                const uint8_t* __restrict__ mask, float* __restrict__ attn)
{
    const int tid = threadIdx.x, wv = tid >> 6, l = tid & 63, lr = l & 31, lh = l >> 5;
    const int bh = blockIdx.z, bb = bh >> 3;
    const int m0 = blockIdx.y * 128 + wv * 32;
    const int n0 = blockIdx.x * 128;
    const unsigned short* qp = q + ((size_t)bh * S + m0 + lr) * DK + 8 * lh;
    short8v a[4];
#pragma unroll
    for (int t = 0; t < 4; ++t)
        a[t] = *reinterpret_cast<const short8v*>(qp + 16 * t);
#pragma unroll
    for (int j = 0; j < 4; ++j) {
        const int n0j = n0 + 32 * j;
        const unsigned short* kp = k + ((size_t)bh * S + n0j + lr) * DK + 8 * lh;
        f32x16 acc = ZERO16;
#pragma unroll
        for (int t = 0; t < 4; ++t) {
            short8v bf = *reinterpret_cast<const short8v*>(kp + 16 * t);
            acc = __builtin_amdgcn_mfma_f32_32x32x16_bf16(a[t], bf, acc, 0, 0, 0);
        }
        const int col = n0j + lr;
#pragma unroll
        for (int r = 0; r < 16; ++r) {
            const int row = m0 + (r & 3) + 8 * (r >> 2) + 4 * lh;
            const uint8_t mk = mask[((size_t)bb * S + row) * S + col];
            attn[((size_t)bh * S + row) * S + col] = mk ? -1e9f : acc[r];
        }
    }
}

// ---------------------------------------------------------------------------
// Fused softmax (in-place on attn, f32) + PV MFMA -> ctx bf16 [b][s][512].
// 8 waves: stage1 each wave owns 2 rows; stage2 wave = (d-tile, K-half).
__global__ __launch_bounds__(512)
void smpv_fused(float* __restrict__ attn, const unsigned short* __restrict__ vt,
                unsigned short* __restrict__ ctx)
{
    __shared__ unsigned short P[16 * 2048];      // bf16, XOR-swizzled rows
    __shared__ float cred[2][4][16][16];
    const int tid = threadIdx.x, wv = tid >> 6, l = tid & 63;
    const int bh = blockIdx.y, q0 = blockIdx.x * 16;
    char* Pc = reinterpret_cast<char*>(P);

#pragma unroll
    for (int rr = 0; rr < 2; ++rr) {
        const int row = 2 * wv + rr;
        float* base = attn + ((size_t)bh * S + q0 + row) * S;
        float4 x[8];
#pragma unroll
        for (int i = 0; i < 8; ++i)
            x[i] = reinterpret_cast<const float4*>(base)[l + 64 * i];
        float m = x[0].x;
#pragma unroll
        for (int i = 0; i < 8; ++i)
            m = fmaxf(m, fmaxf(fmaxf(x[i].x, x[i].y), fmaxf(x[i].z, x[i].w)));
#pragma unroll
        for (int off = 32; off; off >>= 1) m = fmaxf(m, __shfl_xor(m, off));
        float sum = 0.f;
#pragma unroll
        for (int i = 0; i < 8; ++i) {
            x[i].x = __expf(x[i].x - m); x[i].y = __expf(x[i].y - m);
            x[i].z = __expf(x[i].z - m); x[i].w = __expf(x[i].w - m);
            sum += x[i].x + x[i].y + x[i].z + x[i].w;
        }
#pragma unroll
        for (int off = 32; off; off >>= 1) sum += __shfl_xor(sum, off);
        const float inv = 1.0f / sum;
        const int swz = (row & 7) << 4;
#pragma unroll
        for (int i = 0; i < 8; ++i) {
            float4 pv;
            pv.x = x[i].x * inv; pv.y = x[i].y * inv;
            pv.z = x[i].z * inv; pv.w = x[i].w * inv;
            reinterpret_cast<float4*>(base)[l + 64 * i] = pv;
            ushort4 pb;
            pb.x = f2bf(pv.x); pb.y = f2bf(pv.y); pb.z = f2bf(pv.z); pb.w = f2bf(pv.w);
            const int byte = row * 4096 + ((8 * (l + 64 * i)) ^ swz);
            *reinterpret_cast<ushort4*>(Pc + byte) = pb;
        }
    }
    __syncthreads();

    // PV: 16x16x32 MFMA. A: P rows (swizzled LDS), B: vt rows (global/L2).
    const int dt = wv & 3, kh = wv >> 1 >> 1;    // dt = wv&3, kh = wv>>2
    const int lq = l & 15, lg = l >> 4;
    f32x4 acc = {0.f, 0.f, 0.f, 0.f};
    const unsigned short* vb = vt + ((size_t)bh * DK + dt * 16 + lq) * S;
    const int rswz = (lq & 7) << 4;
    for (int s = 0; s < 32; ++s) {
        const int kk0 = kh * 1024 + 32 * s;
        short8v af = *reinterpret_cast<const short8v*>(
            Pc + lq * 4096 + (((kk0 + 8 * lg) * 2) ^ rswz));
        short8v bf = *reinterpret_cast<const short8v*>(vb + kk0 + 8 * lg);
        acc = __builtin_amdgcn_mfma_f32_16x16x32_bf16(af, bf, acc, 0, 0, 0);
    }
#pragma unroll
    for (int r = 0; r < 4; ++r) cred[kh][dt][lg * 4 + r][lq] = acc[r];
    __syncthreads();

    const int b = bh >> 3, h = bh & 7;
    for (int o = tid; o < 1024; o += 512) {
        const int qq = o >> 6, dd = o & 63;
        const float val = cred[0][dd >> 4][qq][dd & 15] + cred[1][dd >> 4][qq][dd & 15];
        ctx[((size_t)(b * S + q0 + qq)) * DM + h * DK + dd] = f2bf(val);
    }
}

// ---------------------------------------------------------------------------
// Output projection: pre = ctx_bf16 @ Wo + bo + resid   (f32 out)
__global__ __launch_bounds__(256)
void out_mfma(const unsigned short* __restrict__ Xc, const unsigned short* __restrict__ Wt,
              const float* __restrict__ bias, const float* __restrict__ resid,
              float* __restrict__ pre)
{
    const int tid = threadIdx.x, wv = tid >> 6, l = tid & 63, lr = l & 31, lh = l >> 5;
    const int m0 = blockIdx.y * 128 + wv * 32;
    const int n0 = blockIdx.x * 64;
    const unsigned short* xp = Xc + (size_t)(m0 + lr) * DM + 8 * lh;
    const unsigned short* w0 = Wt + (size_t)(n0 + lr) * DM + 8 * lh;
    const unsigned short* w1 = w0 + (size_t)32 * DM;
    f32x16 acc0 = ZERO16, acc1 = ZERO16;
#pragma unroll 8
    for (int t = 0; t < 32; ++t) {
        short8v a  = *reinterpret_cast<const short8v*>(xp + 16 * t);
        short8v b0 = *reinterpret_cast<const short8v*>(w0 + 16 * t);
        short8v b1 = *reinterpret_cast<const short8v*>(w1 + 16 * t);
        acc0 = __builtin_amdgcn_mfma_f32_32x32x16_bf16(a, b0, acc0, 0, 0, 0);
        acc1 = __builtin_amdgcn_mfma_f32_32x32x16_bf16(a, b1, acc1, 0, 0, 0);
    }
#pragma unroll
    for (int j = 0; j < 2; ++j) {
        const f32x16 acc = j ? acc1 : acc0;
        const int n = n0 + 32 * j + lr;
        const float bv = bias[n];
#pragma unroll
        for (int r = 0; r < 16; ++r) {
            const int m = m0 + (r & 3) + 8 * (r >> 2) + 4 * lh;
            pre[(size_t)m * DM + n] = acc[r] + bv + resid[(size_t)m * DM + n];
        }
    }
}

// ---------------------------------------------------------------------------
__global__ __launch_bounds__(128)
void ln_kernel(const float* __restrict__ pre, float* __restrict__ out)
{
    const size_t row = blockIdx.x;
    const int tid = threadIdx.x;
    const int wave = tid >> 6;
    float4 x = reinterpret_cast<const float4*>(pre + row * DM)[tid];

    float s = x.x + x.y + x.z + x.w;
#pragma unroll
    for (int off = 32; off; off >>= 1) s += __shfl_xor(s, off);
    __shared__ float r1[2];
    if ((tid & 63) == 0) r1[wave] = s;
    __syncthreads();
    const float mean = (r1[0] + r1[1]) * (1.0f / 512.0f);

    float dx = x.x - mean, dy = x.y - mean, dz = x.z - mean, dw = x.w - mean;
    float sq = dx * dx + dy * dy + dz * dz + dw * dw;
#pragma unroll
    for (int off = 32; off; off >>= 1) sq += __shfl_xor(sq, off);
    __shared__ float r2[2];
    if ((tid & 63) == 0) r2[wave] = sq;
    __syncthreads();
    const float var = (r2[0] + r2[1]) * (1.0f / 512.0f);
    const float inv = rsqrtf(var + 1e-5f);

    float4 y;
    y.x = dx * inv; y.y = dy * inv; y.z = dz * inv; y.w = dw * inv;
    reinterpret_cast<float4*>(out + row * DM)[tid] = y;
}

// ---------------------------------------------------------------------------
extern "C" void kernel_launch(void* const* d_in, const int* in_sizes, int n_in,
                              void* d_out, int out_size, void* d_ws, size_t ws_size,
                              hipStream_t stream)
{
    (void)in_sizes; (void)n_in; (void)out_size; (void)ws_size;

    const float*   Qin  = (const float*)d_in[0];
    const float*   Kin  = (const float*)d_in[1];
    const float*   Vin  = (const float*)d_in[2];
    const uint8_t* mask = (const uint8_t*)d_in[3];
    const float*   Wq   = (const float*)d_in[4];
    const float*   bq   = (const float*)d_in[5];
    const float*   Wk   = (const float*)d_in[6];
    const float*   bk   = (const float*)d_in[7];
    const float*   Wv   = (const float*)d_in[8];
    const float*   bv   = (const float*)d_in[9];
    const float*   Wo   = (const float*)d_in[10];
    const float*   bo   = (const float*)d_in[11];

    float* out  = (float*)d_out;
    float* attn = out + OUT_ELEMS;

    char* w = (char*)d_ws;
    const size_t MB = 1 << 20;
    unsigned short* wt   = (unsigned short*)(w);             // 2 MB (4 matrices)
    unsigned short* qbf  = (unsigned short*)(w + 2  * MB);   // 8 MB
    unsigned short* kbf  = (unsigned short*)(w + 10 * MB);   // 8 MB
    unsigned short* vbf  = (unsigned short*)(w + 18 * MB);   // 8 MB
    unsigned short* vtb  = (unsigned short*)(w + 26 * MB);   // 8 MB
    unsigned short* ctx  = (unsigned short*)(w + 34 * MB);   // 8 MB
    float*          pre  = (float*)(w + 42 * MB);            // 16 MB -> total 58 MB

    unsigned short* wtq = wt;
    unsigned short* wtk = wt + (size_t)DM * DM;
    unsigned short* wtv = wt + 2 * (size_t)DM * DM;
    unsigned short* wto = wt + 3 * (size_t)DM * DM;

    wconv<<<dim3(16, 16, 4), 256, 0, stream>>>(Wq, Wk, Wv, Wo, wt);

    dim3 gProj(DM / 64, ROWS / 128);                    // (8, 64)
    proj_mfma<<<gProj, 256, 0, stream>>>(Qin, wtq, bq, qbf, 0.125f);
    proj_mfma<<<gProj, 256, 0, stream>>>(Kin, wtk, bk, kbf, 1.0f);
    proj_mfma<<<gProj, 256, 0, stream>>>(Vin, wtv, bv, vbf, 1.0f);

    vtrans<<<dim3(S / 64, BH), 256, 0, stream>>>(vbf, vtb);

    score_mfma<<<dim3(S / 128, S / 128, BH), 256, 0, stream>>>(qbf, kbf, mask, attn);

    smpv_fused<<<dim3(S / 16, BH), 512, 0, stream>>>(attn, vtb, ctx);

    out_mfma<<<gProj, 256, 0, stream>>>(ctx, wto, bo, Qin, pre);

    ln_kernel<<<ROWS, 128, 0, stream>>>(pre, out);
}

// Round 3
// 490.040 us; speedup vs baseline: 2.3459x; 1.3052x over previous
//
#include <hip/hip_runtime.h>
#include <hip/hip_bf16.h>
#include <cstdint>
#include <cstddef>

// Round 3: fused score+softmax+PV (single 512MB attn write, P lives in LDS).
//  wconv:      W[k][n] f32 -> Wt[n][k] bf16 (x4)                   (ws)
//  proj3_mfma: q/k/v bf16 [bh][s][64] in one launch (q pre-scaled) (ws)
//  vtrans:     v -> vt [bh][64][s] bf16                            (ws)
//  attn_fused: QK^T -> LDS bf16 -> softmax(+mask) -> attn f32 (once)
//              -> normalized P in LDS -> PV MFMA -> ctx bf16       (ws)
//  out_mfma:   ctx @ Wo + bo + resid -> pre f32                    (ws)
//  ln_kernel:  LayerNorm -> out

typedef __attribute__((ext_vector_type(8)))  short short8v;
typedef __attribute__((ext_vector_type(4)))  float f32x4;
typedef __attribute__((ext_vector_type(16))) float f32x16;

constexpr int DM = 512, S = 2048, BATCH = 4, NHEAD = 8, DK = 64;
constexpr int ROWS = BATCH * S;                 // 8192
constexpr int BH   = BATCH * NHEAD;             // 32
constexpr size_t OUT_ELEMS = (size_t)ROWS * DM; // 4,194,304

#define ZERO16 {0.f,0.f,0.f,0.f,0.f,0.f,0.f,0.f,0.f,0.f,0.f,0.f,0.f,0.f,0.f,0.f}

__device__ __forceinline__ unsigned short f2bf(float f) {
    union { __hip_bfloat16 b; unsigned short u; } c;
    c.b = __float2bfloat16(f);   // RNE
    return c.u;
}
__device__ __forceinline__ float bf2f(unsigned short u) {
    union { float f; unsigned u32; } c;
    c.u32 = (unsigned)u << 16;
    return c.f;
}

// ---------------------------------------------------------------------------
// Transpose-convert the 4 weight matrices: W[512][512] f32 -> Wt[n][k] bf16.
__global__ __launch_bounds__(256)
void wconv(const float* __restrict__ Wq, const float* __restrict__ Wk,
           const float* __restrict__ Wv, const float* __restrict__ Wo,
           unsigned short* __restrict__ wt)
{
    __shared__ float T[32][33];
    const float* srcs[4] = {Wq, Wk, Wv, Wo};
    const float* W = srcs[blockIdx.z];
    unsigned short* out = wt + (size_t)blockIdx.z * DM * DM;
    const int r0 = blockIdx.y * 32, c0 = blockIdx.x * 32;
    const int tid = threadIdx.x;
#pragma unroll
    for (int i = 0; i < 4; ++i) {
        int lin = tid + i * 256; int r = lin >> 5, c = lin & 31;
        T[r][c] = W[(size_t)(r0 + r) * DM + c0 + c];
    }
    __syncthreads();
#pragma unroll
    for (int i = 0; i < 4; ++i) {
        int lin = tid + i * 256; int rn = lin >> 5, ck = lin & 31;
        out[(size_t)(c0 + rn) * DM + r0 + ck] = f2bf(T[ck][rn]);
    }
}

// ---------------------------------------------------------------------------
// All three projections in one launch (blockIdx.z selects q/k/v).
__global__ __launch_bounds__(256)
void proj3_mfma(const float* __restrict__ Qin, const float* __restrict__ Kin,
                const float* __restrict__ Vin, const unsigned short* __restrict__ wt,
                const float* __restrict__ bq, const float* __restrict__ bk,
                const float* __restrict__ bv,
                unsigned short* __restrict__ qo, unsigned short* __restrict__ ko,
                unsigned short* __restrict__ vo)
{
    const int z = blockIdx.z;
    const float* X = (z == 0) ? Qin : (z == 1) ? Kin : Vin;
    const unsigned short* Wt = wt + (size_t)z * DM * DM;
    const float* bias = (z == 0) ? bq : (z == 1) ? bk : bv;
    unsigned short* Y = (z == 0) ? qo : (z == 1) ? ko : vo;
    const float scale = (z == 0) ? 0.125f : 1.0f;

    const int tid = threadIdx.x, wv = tid >> 6, l = tid & 63, lr = l & 31, lh = l >> 5;
    const int m0 = blockIdx.y * 128 + wv * 32;
    const int n0 = blockIdx.x * 64;
    const float* xp = X + (size_t)(m0 + lr) * DM + 8 * lh;
    const unsigned short* w0 = Wt + (size_t)(n0 + lr) * DM + 8 * lh;
    const unsigned short* w1 = w0 + (size_t)32 * DM;
    f32x16 acc0 = ZERO16, acc1 = ZERO16;
#pragma unroll 8
    for (int t = 0; t < 32; ++t) {
        float4 xa = *reinterpret_cast<const float4*>(xp + 16 * t);
        float4 xb = *reinterpret_cast<const float4*>(xp + 16 * t + 4);
        short8v a;
        a[0] = (short)f2bf(xa.x * scale); a[1] = (short)f2bf(xa.y * scale);
        a[2] = (short)f2bf(xa.z * scale); a[3] = (short)f2bf(xa.w * scale);
        a[4] = (short)f2bf(xb.x * scale); a[5] = (short)f2bf(xb.y * scale);
        a[6] = (short)f2bf(xb.z * scale); a[7] = (short)f2bf(xb.w * scale);
        short8v b0 = *reinterpret_cast<const short8v*>(w0 + 16 * t);
        short8v b1 = *reinterpret_cast<const short8v*>(w1 + 16 * t);
        acc0 = __builtin_amdgcn_mfma_f32_32x32x16_bf16(a, b0, acc0, 0, 0, 0);
        acc1 = __builtin_amdgcn_mfma_f32_32x32x16_bf16(a, b1, acc1, 0, 0, 0);
    }
#pragma unroll
    for (int j = 0; j < 2; ++j) {
        const f32x16 acc = j ? acc1 : acc0;
        const int n = n0 + 32 * j + lr;
        const float bvv = bias[n] * scale;
        const int h = n >> 6, d = n & 63;
#pragma unroll
        for (int r = 0; r < 16; ++r) {
            const int m = m0 + (r & 3) + 8 * (r >> 2) + 4 * lh;
            const int b = m >> 11, s = m & (S - 1);
            Y[(((size_t)b * NHEAD + h) * S + s) * DK + d] = f2bf(acc[r] + bvv);
        }
    }
}

// ---------------------------------------------------------------------------
// v[bh][s][64] -> vt[bh][64][s] (bf16 transpose)
__global__ __launch_bounds__(256)
void vtrans(const unsigned short* __restrict__ v, unsigned short* __restrict__ vt)
{
    __shared__ unsigned short T[64][65];
    const int bh = blockIdx.y, s0 = blockIdx.x * 64, tid = threadIdx.x;
#pragma unroll
    for (int i = 0; i < 4; ++i) {
        int lin = tid + i * 256; int sr = lin >> 4, c4 = (lin & 15) * 4;
        ushort4 u = *reinterpret_cast<const ushort4*>(
            v + ((size_t)bh * S + s0 + sr) * DK + c4);
        T[sr][c4] = u.x; T[sr][c4 + 1] = u.y; T[sr][c4 + 2] = u.z; T[sr][c4 + 3] = u.w;
    }
    __syncthreads();
#pragma unroll
    for (int i = 0; i < 4; ++i) {
        int lin = tid + i * 256; int d = lin >> 4, c4 = (lin & 15) * 4;
        ushort4 w;
        w.x = T[c4][d]; w.y = T[c4 + 1][d]; w.z = T[c4 + 2][d]; w.w = T[c4 + 3][d];
        *reinterpret_cast<ushort4*>(vt + ((size_t)bh * DK + d) * S + s0 + c4) = w;
    }
}

// ---------------------------------------------------------------------------
// Fused: QK^T (MFMA) -> LDS raw bf16 scores -> masked softmax -> attn f32
// (single write) + normalized bf16 P in LDS -> PV (MFMA) -> ctx bf16.
// Block: one bh, 16 q-rows, 8 waves.
__global__ __launch_bounds__(512)
void attn_fused(const unsigned short* __restrict__ q,
                const unsigned short* __restrict__ k,
                const unsigned short* __restrict__ vt,
                const uint8_t* __restrict__ mask,
                float* __restrict__ attn,
                unsigned short* __restrict__ ctx)
{
    __shared__ char Pc[16 * 4096];        // 64 KB: 16 rows x 2048 bf16, swizzled
    __shared__ float cred[2][4][16][16];  // 8 KB PV cross-wave reduce
    const int tid = threadIdx.x, wv = tid >> 6, l = tid & 63;
    const int lq = l & 15, lg = l >> 4;
    const int bh = blockIdx.y, q0 = blockIdx.x * 16;
    const int b = bh >> 3, h = bh & 7;

    // ---- Phase 1: QK^T -> raw bf16 scores into LDS (q pre-scaled by 1/8)
    const unsigned short* qp = q + ((size_t)bh * S + q0 + lq) * DK + 8 * lg;
    const short8v af0 = *reinterpret_cast<const short8v*>(qp);
    const short8v af1 = *reinterpret_cast<const short8v*>(qp + 32);
    for (int it = 0; it < 16; ++it) {
        const int n = it * 128 + wv * 16 + lq;
        const unsigned short* kp = k + ((size_t)bh * S + n) * DK + 8 * lg;
        const short8v b0 = *reinterpret_cast<const short8v*>(kp);
        const short8v b1 = *reinterpret_cast<const short8v*>(kp + 32);
        f32x4 acc = {0.f, 0.f, 0.f, 0.f};
        acc = __builtin_amdgcn_mfma_f32_16x16x32_bf16(af0, b0, acc, 0, 0, 0);
        acc = __builtin_amdgcn_mfma_f32_16x16x32_bf16(af1, b1, acc, 0, 0, 0);
#pragma unroll
        for (int r = 0; r < 4; ++r) {
            const int row = lg * 4 + r;
            *reinterpret_cast<unsigned short*>(
                Pc + row * 4096 + ((2 * n) ^ ((row & 7) << 4))) = f2bf(acc[r]);
        }
    }
    __syncthreads();

    // ---- Phase 2: masked softmax per row; write attn once; normalize P
#pragma unroll
    for (int rr = 0; rr < 2; ++rr) {
        const int row = wv * 2 + rr;
        const int grow = q0 + row;
        const int swz = (row & 7) << 4;
        const uint8_t* mrow = mask + ((size_t)b * S + grow) * S;
        float xs[4][8];
        float vmax = -1e30f;
#pragma unroll
        for (int i = 0; i < 4; ++i) {
            const int c = l + 64 * i;                       // 16B chunk index
            const short8v pr = *reinterpret_cast<const short8v*>(
                Pc + row * 4096 + ((c * 16) ^ swz));
            const uint2 mk = *reinterpret_cast<const uint2*>(mrow + 8 * (size_t)c);
#pragma unroll
            for (int j = 0; j < 8; ++j) {
                const unsigned mb =
                    (j < 4 ? (mk.x >> (8 * j)) : (mk.y >> (8 * (j - 4)))) & 0xffu;
                xs[i][j] = mb ? -1e30f : bf2f((unsigned short)pr[j]);
                vmax = fmaxf(vmax, xs[i][j]);
            }
        }
#pragma unroll
        for (int off = 32; off; off >>= 1) vmax = fmaxf(vmax, __shfl_xor(vmax, off));
        float sum = 0.f;
#pragma unroll
        for (int i = 0; i < 4; ++i)
#pragma unroll
            for (int j = 0; j < 8; ++j) {
                xs[i][j] = __expf(xs[i][j] - vmax);
                sum += xs[i][j];
            }
#pragma unroll
        for (int off = 32; off; off >>= 1) sum += __shfl_xor(sum, off);
        const float inv = 1.0f / sum;
        float* arow = attn + ((size_t)bh * S + grow) * S;
#pragma unroll
        for (int i = 0; i < 4; ++i) {
            const int c = l + 64 * i;
            float4 o0, o1;
            o0.x = xs[i][0] * inv; o0.y = xs[i][1] * inv;
            o0.z = xs[i][2] * inv; o0.w = xs[i][3] * inv;
            o1.x = xs[i][4] * inv; o1.y = xs[i][5] * inv;
            o1.z = xs[i][6] * inv; o1.w = xs[i][7] * inv;
            *reinterpret_cast<float4*>(arow + 8 * c)     = o0;
            *reinterpret_cast<float4*>(arow + 8 * c + 4) = o1;
            ushort4 p0, p1;
            p0.x = f2bf(o0.x); p0.y = f2bf(o0.y); p0.z = f2bf(o0.z); p0.w = f2bf(o0.w);
            p1.x = f2bf(o1.x); p1.y = f2bf(o1.y); p1.z = f2bf(o1.z); p1.w = f2bf(o1.w);
            char* pb = Pc + row * 4096 + ((c * 16) ^ swz);
            *reinterpret_cast<ushort4*>(pb)     = p0;
            *reinterpret_cast<ushort4*>(pb + 8) = p1;
        }
    }
    __syncthreads();

    // ---- Phase 3: PV. wave = (d-tile dt, K-half kh). A: P (LDS), B: vt.
    const int dt = wv & 3, kh = wv >> 2;
    f32x4 acc = {0.f, 0.f, 0.f, 0.f};
    const unsigned short* vb = vt + ((size_t)bh * DK + dt * 16 + lq) * S;
    const int rswz = (lq & 7) << 4;
    for (int s = 0; s < 32; ++s) {
        const int kk0 = kh * 1024 + 32 * s;
        const short8v a = *reinterpret_cast<const short8v*>(
            Pc + lq * 4096 + ((2 * (kk0 + 8 * lg)) ^ rswz));
        const short8v bf = *reinterpret_cast<const short8v*>(vb + kk0 + 8 * lg);
        acc = __builtin_amdgcn_mfma_f32_16x16x32_bf16(a, bf, acc, 0, 0, 0);
    }
#pragma unroll
    for (int r = 0; r < 4; ++r) cred[kh][dt][lg * 4 + r][lq] = acc[r];
    __syncthreads();

    for (int o = tid; o < 1024; o += 512) {
        const int qq = o >> 6, dd = o & 63;
        const float val = cred[0][dd >> 4][qq][dd & 15] + cred[1][dd >> 4][qq][dd & 15];
        ctx[((size_t)(b * S + q0 + qq)) * DM + h * DK + dd] = f2bf(val);
    }
}

// ---------------------------------------------------------------------------
// Output projection: pre = ctx_bf16 @ Wo + bo + resid   (f32 out)
__global__ __launch_bounds__(256)
void out_mfma(const unsigned short* __restrict__ Xc, const unsigned short* __restrict__ Wt,
              const float* __restrict__ bias, const float* __restrict__ resid,
              float* __restrict__ pre)
{
    const int tid = threadIdx.x, wv = tid >> 6, l = tid & 63, lr = l & 31, lh = l >> 5;
    const int m0 = blockIdx.y * 128 + wv * 32;
    const int n0 = blockIdx.x * 64;
    const unsigned short* xp = Xc + (size_t)(m0 + lr) * DM + 8 * lh;
    const unsigned short* w0 = Wt + (size_t)(n0 + lr) * DM + 8 * lh;
    const unsigned short* w1 = w0 + (size_t)32 * DM;
    f32x16 acc0 = ZERO16, acc1 = ZERO16;
#pragma unroll 8
    for (int t = 0; t < 32; ++t) {
        short8v a  = *reinterpret_cast<const short8v*>(xp + 16 * t);
        short8v b0 = *reinterpret_cast<const short8v*>(w0 + 16 * t);
        short8v b1 = *reinterpret_cast<const short8v*>(w1 + 16 * t);
        acc0 = __builtin_amdgcn_mfma_f32_32x32x16_bf16(a, b0, acc0, 0, 0, 0);
        acc1 = __builtin_amdgcn_mfma_f32_32x32x16_bf16(a, b1, acc1, 0, 0, 0);
    }
#pragma unroll
    for (int j = 0; j < 2; ++j) {
        const f32x16 acc = j ? acc1 : acc0;
        const int n = n0 + 32 * j + lr;
        const float bv = bias[n];
#pragma unroll
        for (int r = 0; r < 16; ++r) {
            const int m = m0 + (r & 3) + 8 * (r >> 2) + 4 * lh;
            pre[(size_t)m * DM + n] = acc[r] + bv + resid[(size_t)m * DM + n];
        }
    }
}

// ---------------------------------------------------------------------------
__global__ __launch_bounds__(128)
void ln_kernel(const float* __restrict__ pre, float* __restrict__ out)
{
    const size_t row = blockIdx.x;
    const int tid = threadIdx.x;
    const int wave = tid >> 6;
    float4 x = reinterpret_cast<const float4*>(pre + row * DM)[tid];

    float s = x.x + x.y + x.z + x.w;
#pragma unroll
    for (int off = 32; off; off >>= 1) s += __shfl_xor(s, off);
    __shared__ float r1[2];
    if ((tid & 63) == 0) r1[wave] = s;
    __syncthreads();
    const float mean = (r1[0] + r1[1]) * (1.0f / 512.0f);

    float dx = x.x - mean, dy = x.y - mean, dz = x.z - mean, dw = x.w - mean;
    float sq = dx * dx + dy * dy + dz * dz + dw * dw;
#pragma unroll
    for (int off = 32; off; off >>= 1) sq += __shfl_xor(sq, off);
    __shared__ float r2[2];
    if ((tid & 63) == 0) r2[wave] = sq;
    __syncthreads();
    const float var = (r2[0] + r2[1]) * (1.0f / 512.0f);
    const float inv = rsqrtf(var + 1e-5f);

    float4 y;
    y.x = dx * inv; y.y = dy * inv; y.z = dz * inv; y.w = dw * inv;
    reinterpret_cast<float4*>(out + row * DM)[tid] = y;
}

// ---------------------------------------------------------------------------
extern "C" void kernel_launch(void* const* d_in, const int* in_sizes, int n_in,
                              void* d_out, int out_size, void* d_ws, size_t ws_size,
                              hipStream_t stream)
{
    (void)in_sizes; (void)n_in; (void)out_size; (void)ws_size;

    const float*   Qin  = (const float*)d_in[0];
    const float*   Kin  = (const float*)d_in[1];
    const float*   Vin  = (const float*)d_in[2];
    const uint8_t* mask = (const uint8_t*)d_in[3];
    const float*   Wq   = (const float*)d_in[4];
    const float*   bq   = (const float*)d_in[5];
    const float*   Wk   = (const float*)d_in[6];
    const float*   bk   = (const float*)d_in[7];
    const float*   Wv   = (const float*)d_in[8];
    const float*   bv   = (const float*)d_in[9];
    const float*   Wo   = (const float*)d_in[10];
    const float*   bo   = (const float*)d_in[11];

    float* out  = (float*)d_out;
    float* attn = out + OUT_ELEMS;

    char* w = (char*)d_ws;
    const size_t MB = 1 << 20;
    unsigned short* wt   = (unsigned short*)(w);             // 2 MB (4 matrices)
    unsigned short* qbf  = (unsigned short*)(w + 2  * MB);   // 8 MB
    unsigned short* kbf  = (unsigned short*)(w + 10 * MB);   // 8 MB
    unsigned short* vbf  = (unsigned short*)(w + 18 * MB);   // 8 MB
    unsigned short* vtb  = (unsigned short*)(w + 26 * MB);   // 8 MB
    unsigned short* ctx  = (unsigned short*)(w + 34 * MB);   // 8 MB
    float*          pre  = (float*)(w + 42 * MB);            // 16 MB -> 58 MB

    unsigned short* wto = wt + 3 * (size_t)DM * DM;

    wconv<<<dim3(16, 16, 4), 256, 0, stream>>>(Wq, Wk, Wv, Wo, wt);

    proj3_mfma<<<dim3(DM / 64, ROWS / 128, 3), 256, 0, stream>>>(
        Qin, Kin, Vin, wt, bq, bk, bv, qbf, kbf, vbf);

    vtrans<<<dim3(S / 64, BH), 256, 0, stream>>>(vbf, vtb);

    attn_fused<<<dim3(S / 16, BH), 512, 0, stream>>>(qbf, kbf, vtb, mask, attn, ctx);

    out_mfma<<<dim3(DM / 64, ROWS / 128), 256, 0, stream>>>(ctx, wto, bo, Qin, pre);

    ln_kernel<<<ROWS, 128, 0, stream>>>(pre, out);
}

// Round 4
// 325.517 us; speedup vs baseline: 3.5315x; 1.5054x over previous
//
#include <hip/hip_runtime.h>
#include <hip/hip_bf16.h>
#include <cstdint>
#include <cstddef>

// Round 4: fused attention with packed operands + write-in-PV-loop.
//  wconv:      W -> Wt[n][k] bf16 (x4)
//  maskpack:   bool mask -> bitmask u32[B*S][64]  (16MB -> 2MB, L2-resident)
//  proj3_mfma: q [bh][s][64]; k,v emitted in MFMA-fragment-packed layouts
//  attn_fused: QK^T -> LDS bf16 -> masked softmax (LDS only) ->
//              PV MFMA with interleaved nontemporal attn f32 writes -> ctx
//  out_mfma:   ctx @ Wo + bo + resid -> pre f32
//  ln_kernel:  LayerNorm -> out

typedef __attribute__((ext_vector_type(8)))  short short8v;
typedef __attribute__((ext_vector_type(2)))  float f32x2;
typedef __attribute__((ext_vector_type(4)))  float f32x4;
typedef __attribute__((ext_vector_type(16))) float f32x16;

constexpr int DM = 512, S = 2048, BATCH = 4, NHEAD = 8, DK = 64;
constexpr int ROWS = BATCH * S;                 // 8192
constexpr int BH   = BATCH * NHEAD;             // 32
constexpr size_t OUT_ELEMS = (size_t)ROWS * DM; // 4,194,304
constexpr size_t HFRAG = 131072;                // elems per bh in packed k/v (2048*64)

#define ZERO16 {0.f,0.f,0.f,0.f,0.f,0.f,0.f,0.f,0.f,0.f,0.f,0.f,0.f,0.f,0.f,0.f}

__device__ __forceinline__ unsigned short f2bf(float f) {
    union { __hip_bfloat16 b; unsigned short u; } c;
    c.b = __float2bfloat16(f);   // RNE
    return c.u;
}
__device__ __forceinline__ float bf2f(unsigned short u) {
    union { float f; unsigned u32; } c;
    c.u32 = (unsigned)u << 16;
    return c.f;
}

// ---------------------------------------------------------------------------
__global__ __launch_bounds__(256)
void wconv(const float* __restrict__ Wq, const float* __restrict__ Wk,
           const float* __restrict__ Wv, const float* __restrict__ Wo,
           unsigned short* __restrict__ wt)
{
    __shared__ float T[32][33];
    const float* srcs[4] = {Wq, Wk, Wv, Wo};
    const float* W = srcs[blockIdx.z];
    unsigned short* out = wt + (size_t)blockIdx.z * DM * DM;
    const int r0 = blockIdx.y * 32, c0 = blockIdx.x * 32;
    const int tid = threadIdx.x;
#pragma unroll
    for (int i = 0; i < 4; ++i) {
        int lin = tid + i * 256; int r = lin >> 5, c = lin & 31;
        T[r][c] = W[(size_t)(r0 + r) * DM + c0 + c];
    }
    __syncthreads();
#pragma unroll
    for (int i = 0; i < 4; ++i) {
        int lin = tid + i * 256; int rn = lin >> 5, ck = lin & 31;
        out[(size_t)(c0 + rn) * DM + r0 + ck] = f2bf(T[ck][rn]);
    }
}

// ---------------------------------------------------------------------------
// Pack bool mask to bits: mb[row][w] bit k <-> mask[row][32w+k]!=0.
__global__ __launch_bounds__(256)
void maskpack(const uint8_t* __restrict__ mask, unsigned* __restrict__ mb)
{
    const int t = threadIdx.x;
    const int row = blockIdx.x * 4 + (t >> 6);
    const int w = t & 63;
    const uint8_t* src = mask + (size_t)row * S + 32 * w;
    const uint4 a = *reinterpret_cast<const uint4*>(src);
    const uint4 b = *reinterpret_cast<const uint4*>(src + 16);
    const unsigned m8[8] = {a.x, a.y, a.z, a.w, b.x, b.y, b.z, b.w};
    unsigned bits = 0;
#pragma unroll
    for (int k2 = 0; k2 < 32; ++k2)
        bits |= (((m8[k2 >> 2] >> (8 * (k2 & 3))) & 0xffu) ? 1u : 0u) << k2;
    mb[(size_t)row * 64 + w] = bits;
}

// ---------------------------------------------------------------------------
// Projections. q: [bh][s][64]. k packed for QK^T B-frags:
//   kpack[bh*131072 + (s>>4)*1024 + (d>>5)*512 + ((s&15)+16*((d&31)>>3))*8 + (d&7)]
// v packed for PV B-frags:
//   vpack[bh*131072 + (s>>5)*2048 + (d>>4)*512 + ((d&15)+16*((s&31)>>3))*8 + (s&7)]
__global__ __launch_bounds__(256)
void proj3_mfma(const float* __restrict__ Qin, const float* __restrict__ Kin,
                const float* __restrict__ Vin, const unsigned short* __restrict__ wt,
                const float* __restrict__ bq, const float* __restrict__ bk,
                const float* __restrict__ bv,
                unsigned short* __restrict__ qo, unsigned short* __restrict__ ko,
                unsigned short* __restrict__ vo)
{
    const int z = blockIdx.z;
    const float* X = (z == 0) ? Qin : (z == 1) ? Kin : Vin;
    const unsigned short* Wt = wt + (size_t)z * DM * DM;
    const float* bias = (z == 0) ? bq : (z == 1) ? bk : bv;
    unsigned short* Y = (z == 0) ? qo : (z == 1) ? ko : vo;
    const float scale = (z == 0) ? 0.125f : 1.0f;

    const int tid = threadIdx.x, wv = tid >> 6, l = tid & 63, lr = l & 31, lh = l >> 5;
    const int m0 = blockIdx.y * 128 + wv * 32;
    const int n0 = blockIdx.x * 64;
    const float* xp = X + (size_t)(m0 + lr) * DM + 8 * lh;
    const unsigned short* w0 = Wt + (size_t)(n0 + lr) * DM + 8 * lh;
    const unsigned short* w1 = w0 + (size_t)32 * DM;
    f32x16 acc0 = ZERO16, acc1 = ZERO16;
#pragma unroll 8
    for (int t = 0; t < 32; ++t) {
        float4 xa = *reinterpret_cast<const float4*>(xp + 16 * t);
        float4 xb = *reinterpret_cast<const float4*>(xp + 16 * t + 4);
        short8v a;
        a[0] = (short)f2bf(xa.x * scale); a[1] = (short)f2bf(xa.y * scale);
        a[2] = (short)f2bf(xa.z * scale); a[3] = (short)f2bf(xa.w * scale);
        a[4] = (short)f2bf(xb.x * scale); a[5] = (short)f2bf(xb.y * scale);
        a[6] = (short)f2bf(xb.z * scale); a[7] = (short)f2bf(xb.w * scale);
        short8v b0 = *reinterpret_cast<const short8v*>(w0 + 16 * t);
        short8v b1 = *reinterpret_cast<const short8v*>(w1 + 16 * t);
        acc0 = __builtin_amdgcn_mfma_f32_32x32x16_bf16(a, b0, acc0, 0, 0, 0);
        acc1 = __builtin_amdgcn_mfma_f32_32x32x16_bf16(a, b1, acc1, 0, 0, 0);
    }
#pragma unroll
    for (int j = 0; j < 2; ++j) {
        const f32x16 acc = j ? acc1 : acc0;
        const int n = n0 + 32 * j + lr;
        const float bvv = bias[n] * scale;
        const int h = n >> 6, d = n & 63;
#pragma unroll
        for (int r = 0; r < 16; ++r) {
            const int m = m0 + (r & 3) + 8 * (r >> 2) + 4 * lh;
            const int bb = m >> 11, s = m & (S - 1);
            const int bh = bb * NHEAD + h;
            const unsigned short val = f2bf(acc[r] + bvv);
            size_t idx;
            if (z == 0)
                idx = ((size_t)bh * S + s) * DK + d;
            else if (z == 1)
                idx = (size_t)bh * HFRAG + (size_t)(s >> 4) * 1024 + (size_t)(d >> 5) * 512
                      + (size_t)(((s & 15) + 16 * ((d & 31) >> 3)) << 3) + (d & 7);
            else
                idx = (size_t)bh * HFRAG + (size_t)(s >> 5) * 2048 + (size_t)(d >> 4) * 512
                      + (size_t)(((d & 15) + 16 * ((s & 31) >> 3)) << 3) + (s & 7);
            Y[idx] = val;
        }
    }
}

// ---------------------------------------------------------------------------
// Fused attention. Block: one bh x 16 q-rows, 8 waves, LDS P 64KB.
__global__ __launch_bounds__(512)
void attn_fused(const unsigned short* __restrict__ q,
                const unsigned short* __restrict__ kpack,
                const unsigned short* __restrict__ vpack,
                const unsigned* __restrict__ mbits,
                float* __restrict__ attn,
                unsigned short* __restrict__ ctx)
{
    __shared__ char Pc[16 * 4096];        // 64 KB: 16 rows x 2048 bf16, swizzled
    __shared__ float cred[2][4][16][16];  // 8 KB PV cross-wave reduce
    const int tid = threadIdx.x, wv = tid >> 6, l = tid & 63;
    const int lq = l & 15, lg = l >> 4;
    const int bh = blockIdx.y, q0 = blockIdx.x * 16;
    const int b = bh >> 3, h = bh & 7;

    // ---- Phase 1: QK^T -> raw bf16 scores into LDS (q pre-scaled by 1/8)
    const unsigned short* qp = q + ((size_t)bh * S + q0 + lq) * DK + 8 * lg;
    const short8v af0 = *reinterpret_cast<const short8v*>(qp);
    const short8v af1 = *reinterpret_cast<const short8v*>(qp + 32);
    const unsigned short* kbase = kpack + (size_t)bh * HFRAG + (size_t)l * 8;
#pragma unroll 4
    for (int it = 0; it < 16; ++it) {
        const int c = it * 8 + wv;                       // k-chunk of 16 rows
        const unsigned short* kc = kbase + (size_t)c * 1024;
        const short8v b0 = *reinterpret_cast<const short8v*>(kc);
        const short8v b1 = *reinterpret_cast<const short8v*>(kc + 512);
        f32x4 acc = {0.f, 0.f, 0.f, 0.f};
        acc = __builtin_amdgcn_mfma_f32_16x16x32_bf16(af0, b0, acc, 0, 0, 0);
        acc = __builtin_amdgcn_mfma_f32_16x16x32_bf16(af1, b1, acc, 0, 0, 0);
        const int col = c * 16 + lq;
#pragma unroll
        for (int r = 0; r < 4; ++r) {
            const int row = lg * 4 + r;
            *reinterpret_cast<unsigned short*>(
                Pc + row * 4096 + ((2 * col) ^ ((row & 7) << 4))) = f2bf(acc[r]);
        }
    }
    __syncthreads();

    // ---- Phase 2: masked softmax per row (LDS only; no global write)
#pragma unroll
    for (int rr = 0; rr < 2; ++rr) {
        const int row = wv * 2 + rr;
        const int grow = q0 + row;
        const int swz = (row & 7) << 4;
        const unsigned mk = mbits[((size_t)b * S + grow) * 64 + l]; // cols 32l..32l+31
        float xs[4][8];
        float vmax = -1e30f;
#pragma unroll
        for (int i = 0; i < 4; ++i) {
            const int c = 4 * l + i;                     // 16B chunk: cols 8c..8c+7
            const short8v pr = *reinterpret_cast<const short8v*>(
                Pc + row * 4096 + ((16 * c) ^ swz));
#pragma unroll
            for (int j = 0; j < 8; ++j) {
                const bool masked = (mk >> (8 * i + j)) & 1u;
                xs[i][j] = masked ? -1e30f : bf2f((unsigned short)pr[j]);
                vmax = fmaxf(vmax, xs[i][j]);
            }
        }
#pragma unroll
        for (int off = 32; off; off >>= 1) vmax = fmaxf(vmax, __shfl_xor(vmax, off));
        float sum = 0.f;
#pragma unroll
        for (int i = 0; i < 4; ++i)
#pragma unroll
            for (int j = 0; j < 8; ++j) {
                xs[i][j] = __expf(xs[i][j] - vmax);
                sum += xs[i][j];
            }
#pragma unroll
        for (int off = 32; off; off >>= 1) sum += __shfl_xor(sum, off);
        const float inv = 1.0f / sum;
#pragma unroll
        for (int i = 0; i < 4; ++i) {
            const int c = 4 * l + i;
            ushort4 p0, p1;
            p0.x = f2bf(xs[i][0] * inv); p0.y = f2bf(xs[i][1] * inv);
            p0.z = f2bf(xs[i][2] * inv); p0.w = f2bf(xs[i][3] * inv);
            p1.x = f2bf(xs[i][4] * inv); p1.y = f2bf(xs[i][5] * inv);
            p1.z = f2bf(xs[i][6] * inv); p1.w = f2bf(xs[i][7] * inv);
            char* pb = Pc + row * 4096 + ((16 * c) ^ swz);
            *reinterpret_cast<ushort4*>(pb)     = p0;
            *reinterpret_cast<ushort4*>(pb + 8) = p1;
        }
    }
    __syncthreads();

    // ---- Phase 3: PV MFMA + interleaved nontemporal attn f32 writes.
    const int dt = wv & 3, kh = wv >> 2;
    const int rswz = (lq & 7) << 4;
    f32x4 acc = {0.f, 0.f, 0.f, 0.f};
    const unsigned short* vbase = vpack + (size_t)bh * HFRAG + dt * 512 + (size_t)l * 8;
    const int wrow = 8 * kh + 2 * dt + (l >> 5);         // this lane's attn row
    const int wswz = (wrow & 7) << 4;
    const int lc = l & 31;
    float* arow = attn + ((size_t)bh * S + q0 + wrow) * S;
#pragma unroll 4
    for (int s = 0; s < 32; ++s) {
        const int kk0 = kh * 1024 + 32 * s;
        const short8v a = *reinterpret_cast<const short8v*>(
            Pc + lq * 4096 + ((2 * (kk0 + 8 * lg)) ^ rswz));
        const short8v bf = *reinterpret_cast<const short8v*>(
            vbase + (size_t)(kh * 32 + s) * 2048);
        acc = __builtin_amdgcn_mfma_f32_16x16x32_bf16(a, bf, acc, 0, 0, 0);
        // attn write: cols 64s+2lc of row wrow, values from normalized bf16 P
        const unsigned pw = *reinterpret_cast<const unsigned*>(
            Pc + wrow * 4096 + ((128 * s + 4 * lc) ^ wswz));
        f32x2 st;
        st[0] = bf2f((unsigned short)(pw & 0xffffu));
        st[1] = bf2f((unsigned short)(pw >> 16));
        __builtin_nontemporal_store(st,
            reinterpret_cast<f32x2*>(arow + 64 * s + 2 * lc));
    }
#pragma unroll
    for (int r = 0; r < 4; ++r) cred[kh][dt][lg * 4 + r][lq] = acc[r];
    __syncthreads();

    for (int o = tid; o < 1024; o += 512) {
        const int qq = o >> 6, dd = o & 63;
        const float val = cred[0][dd >> 4][qq][dd & 15] + cred[1][dd >> 4][qq][dd & 15];
        ctx[((size_t)(b * S + q0 + qq)) * DM + h * DK + dd] = f2bf(val);
    }
}

// ---------------------------------------------------------------------------
__global__ __launch_bounds__(256)
void out_mfma(const unsigned short* __restrict__ Xc, const unsigned short* __restrict__ Wt,
              const float* __restrict__ bias, const float* __restrict__ resid,
              float* __restrict__ pre)
{
    const int tid = threadIdx.x, wv = tid >> 6, l = tid & 63, lr = l & 31, lh = l >> 5;
    const int m0 = blockIdx.y * 128 + wv * 32;
    const int n0 = blockIdx.x * 64;
    const unsigned short* xp = Xc + (size_t)(m0 + lr) * DM + 8 * lh;
    const unsigned short* w0 = Wt + (size_t)(n0 + lr) * DM + 8 * lh;
    const unsigned short* w1 = w0 + (size_t)32 * DM;
    f32x16 acc0 = ZERO16, acc1 = ZERO16;
#pragma unroll 8
    for (int t = 0; t < 32; ++t) {
        short8v a  = *reinterpret_cast<const short8v*>(xp + 16 * t);
        short8v b0 = *reinterpret_cast<const short8v*>(w0 + 16 * t);
        short8v b1 = *reinterpret_cast<const short8v*>(w1 + 16 * t);
        acc0 = __builtin_amdgcn_mfma_f32_32x32x16_bf16(a, b0, acc0, 0, 0, 0);
        acc1 = __builtin_amdgcn_mfma_f32_32x32x16_bf16(a, b1, acc1, 0, 0, 0);
    }
#pragma unroll
    for (int j = 0; j < 2; ++j) {
        const f32x16 acc = j ? acc1 : acc0;
        const int n = n0 + 32 * j + lr;
        const float bv = bias[n];
#pragma unroll
        for (int r = 0; r < 16; ++r) {
            const int m = m0 + (r & 3) + 8 * (r >> 2) + 4 * lh;
            pre[(size_t)m * DM + n] = acc[r] + bv + resid[(size_t)m * DM + n];
        }
    }
}

// ---------------------------------------------------------------------------
__global__ __launch_bounds__(128)
void ln_kernel(const float* __restrict__ pre, float* __restrict__ out)
{
    const size_t row = blockIdx.x;
    const int tid = threadIdx.x;
    const int wave = tid >> 6;
    float4 x = reinterpret_cast<const float4*>(pre + row * DM)[tid];

    float s = x.x + x.y + x.z + x.w;
#pragma unroll
    for (int off = 32; off; off >>= 1) s += __shfl_xor(s, off);
    __shared__ float r1[2];
    if ((tid & 63) == 0) r1[wave] = s;
    __syncthreads();
    const float mean = (r1[0] + r1[1]) * (1.0f / 512.0f);

    float dx = x.x - mean, dy = x.y - mean, dz = x.z - mean, dw = x.w - mean;
    float sq = dx * dx + dy * dy + dz * dz + dw * dw;
#pragma unroll
    for (int off = 32; off; off >>= 1) sq += __shfl_xor(sq, off);
    __shared__ float r2[2];
    if ((tid & 63) == 0) r2[wave] = sq;
    __syncthreads();
    const float var = (r2[0] + r2[1]) * (1.0f / 512.0f);
    const float inv = rsqrtf(var + 1e-5f);

    float4 y;
    y.x = dx * inv; y.y = dy * inv; y.z = dz * inv; y.w = dw * inv;
    reinterpret_cast<float4*>(out + row * DM)[tid] = y;
}

// ---------------------------------------------------------------------------
extern "C" void kernel_launch(void* const* d_in, const int* in_sizes, int n_in,
                              void* d_out, int out_size, void* d_ws, size_t ws_size,
                              hipStream_t stream)
{
    (void)in_sizes; (void)n_in; (void)out_size; (void)ws_size;

    const float*   Qin  = (const float*)d_in[0];
    const float*   Kin  = (const float*)d_in[1];
    const float*   Vin  = (const float*)d_in[2];
    const uint8_t* mask = (const uint8_t*)d_in[3];
    const float*   Wq   = (const float*)d_in[4];
    const float*   bq   = (const float*)d_in[5];
    const float*   Wk   = (const float*)d_in[6];
    const float*   bk   = (const float*)d_in[7];
    const float*   Wv   = (const float*)d_in[8];
    const float*   bv   = (const float*)d_in[9];
    const float*   Wo   = (const float*)d_in[10];
    const float*   bo   = (const float*)d_in[11];

    float* out  = (float*)d_out;
    float* attn = out + OUT_ELEMS;

    char* w = (char*)d_ws;
    const size_t MB = 1 << 20;
    unsigned short* wt    = (unsigned short*)(w);             // 2 MB (4 matrices)
    unsigned short* qbf   = (unsigned short*)(w + 2  * MB);   // 8 MB
    unsigned short* kpack = (unsigned short*)(w + 10 * MB);   // 8 MB
    unsigned short* vpack = (unsigned short*)(w + 18 * MB);   // 8 MB
    unsigned short* ctx   = (unsigned short*)(w + 26 * MB);   // 8 MB
    float*          pre   = (float*)(w + 34 * MB);            // 16 MB
    unsigned*       mbits = (unsigned*)(w + 50 * MB);         // 2 MB -> 52 MB

    unsigned short* wto = wt + 3 * (size_t)DM * DM;

    wconv<<<dim3(16, 16, 4), 256, 0, stream>>>(Wq, Wk, Wv, Wo, wt);

    maskpack<<<ROWS / 4, 256, 0, stream>>>(mask, mbits);

    proj3_mfma<<<dim3(DM / 64, ROWS / 128, 3), 256, 0, stream>>>(
        Qin, Kin, Vin, wt, bq, bk, bv, qbf, kpack, vpack);

    attn_fused<<<dim3(S / 16, BH), 512, 0, stream>>>(qbf, kpack, vpack, mbits, attn, ctx);

    out_mfma<<<dim3(DM / 64, ROWS / 128), 256, 0, stream>>>(ctx, wto, bo, Qin, pre);

    ln_kernel<<<ROWS, 128, 0, stream>>>(pre, out);
}